// Round 10
// baseline (477.932 us; speedup 1.0000x reference)
//
#include <hip/hip_runtime.h>

// PPNet forward, round 12: r9 + T14 async-STAGE of the h tile.
// Evidence ledger:
//  - r9 (2-deep B prefetch): F0 180->138us, MfmaUtil 12.6, hbm 114MB, no spill
//    at 128 arch + 64 AGPR = 192 of the 256 budget. ILP-at-2-waves/SIMD is the
//    productive lever (all occupancy plays failed: spill or halved ILP).
//  - Remaining exposed latency in F0: the h0 tile global load (64MB grid-wide)
//    issues cold between g2 and the BN epilogue, behind a barrier.
// => This round: issue h-tile loads to REGISTERS at kernel start (before the
//    first barrier) so ~2 full GEMM phases of MFMA hide the HBM/L2 latency;
//    after g2's barrier only the LDS writes remain. +32 VGPR (N=256: 8x uint4)
//    -> 224 total, inside the proven no-spill envelope (<=224 ok, ~274 spills).
// Falsifier: hbm_bytes > 150MB on F0 = spill -> revert to r9.

typedef __attribute__((ext_vector_type(8))) short short8;
typedef __attribute__((ext_vector_type(4))) float floatx4;

#define BATCH 32768
#define NDOM 4
#define TM 64

__device__ __forceinline__ unsigned short f2b(float f) {
    unsigned u = __float_as_uint(f);
    u += 0x7fffu + ((u >> 16) & 1u);  // round-to-nearest-even
    return (unsigned short)(u >> 16);
}
__device__ __forceinline__ float b2f(unsigned short h) {
    return __uint_as_float(((unsigned)h) << 16);
}

// ---------------------------------------------------------------------------
// Shared GEMM phase: acc += A(lds,swizzled) @ B(global rows, K-contiguous),
// with 2-deep B prefetch. K, CT compile-time; loop fully unrolled.
template <int K, int CT>
__device__ __forceinline__ void gemm_phase(const unsigned short* lA,
                                           const unsigned short* __restrict__ Bp,
                                           int lrow, int lq, floatx4 (&acc)[4][CT]) {
    constexpr int G = K / 8;
    short8 b0[CT], b1[CT];
#pragma unroll
    for (int ct = 0; ct < CT; ct++)
        b0[ct] = *(const short8*)(Bp + (long long)(ct * 16 + lrow) * K + lq * 8);
    if constexpr (K > 32) {
#pragma unroll
        for (int ct = 0; ct < CT; ct++)
            b1[ct] = *(const short8*)(Bp + (long long)(ct * 16 + lrow) * K + 32 + lq * 8);
    }
#pragma unroll
    for (int k0 = 0; k0 < K; k0 += 32) {
        short8 a[4];
#pragma unroll
        for (int rt = 0; rt < 4; rt++) {
            int m = rt * 16 + lrow;
            a[rt] = *(const short8*)&lA[(m * G + (((k0 >> 3) | lq) ^ (m & 7))) * 8];
        }
        short8 bn[CT];
        if (k0 + 64 < K) {  // compile-time (unrolled)
#pragma unroll
            for (int ct = 0; ct < CT; ct++)
                bn[ct] = *(const short8*)(Bp + (long long)(ct * 16 + lrow) * K + k0 + 64 + lq * 8);
        }
#pragma unroll
        for (int rt = 0; rt < 4; rt++)
#pragma unroll
            for (int ct = 0; ct < CT; ct++)
                acc[rt][ct] = __builtin_amdgcn_mfma_f32_16x16x32_bf16(a[rt], b0[ct], acc[rt][ct], 0, 0, 0);
#pragma unroll
        for (int ct = 0; ct < CT; ct++) {
            b0[ct] = b1[ct];
            if (k0 + 64 < K) b1[ct] = bn[ct];
        }
    }
}

// ---------------------------------------------------------------------------
// Weight prep: fp32 (D,K,N) -> bf16 (D,N,K) packed; zero stat accumulators.
struct MatDesc { const float* src; unsigned K, N, pfx, total; };
struct PrepArgs { MatDesc m[9]; float* stats; unsigned statsN; unsigned grand; };

__global__ __launch_bounds__(256) void prep_k(PrepArgs a, unsigned short* __restrict__ wt) {
    unsigned e = blockIdx.x * 256 + threadIdx.x;
    if (e < a.statsN) a.stats[e] = 0.f;
    if (e >= a.grand) return;
    int j = 0;
    while (j < 8 && e >= a.m[j].pfx + a.m[j].total) j++;
    const unsigned K = a.m[j].K, N = a.m[j].N;
    const unsigned local = e - a.m[j].pfx;
    const unsigned kn = K * N;
    const unsigned d = local / kn;
    const unsigned r2 = local - d * kn;
    const unsigned n = r2 / K;
    const unsigned k = r2 - n * K;
    wt[e] = f2b(a.m[j].src[((long long)d * K + k) * N + n]);
}

// ---------------------------------------------------------------------------
__global__ __launch_bounds__(256) void embed_k(const int* __restrict__ idi, const int* __restrict__ agi,
                                               const float* __restrict__ idt, const float* __restrict__ agt,
                                               unsigned short* __restrict__ gin) {
    int t = blockIdx.x * 256 + threadIdx.x;  // B*16 threads, one per (b, 16-elem slot)
    int b = t >> 4, slot = t & 15;
    int f = slot & 7;
    const int* ip = (slot < 8) ? idi : agi;
    const float* tab = (slot < 8) ? idt : agt;
    int ix = ip[b * 8 + f];
    const float* src = tab + ((long long)f * 100000 + ix) * 16;
    unsigned short tmp[16];
#pragma unroll
    for (int j = 0; j < 16; j++) tmp[j] = f2b(src[j]);
    unsigned short* dst = gin + (long long)b * 256 + slot * 16;
    *(uint4*)dst = *(const uint4*)tmp;
    *(uint4*)(dst + 8) = *(const uint4*)(tmp + 8);
}

// ---------------------------------------------------------------------------
// h0_k: h0 = gin @ Wm0, stats0 atomics, store h0 bf16.
__global__ __launch_bounds__(256, 2) void h0_k(
    const unsigned short* __restrict__ gin,
    const unsigned short* __restrict__ Wm,   // [d][256][256]
    float* __restrict__ gsum, float* __restrict__ gssq,
    unsigned short* __restrict__ hOut) {     // [d][B][256]
    __shared__ __align__(16) unsigned short tA[TM * 256];
    const int t = threadIdx.x;
    const int d = blockIdx.y;
    const int m0 = blockIdx.x * TM;
    const unsigned short* Xp = gin + (long long)m0 * 256;
#pragma unroll
    for (int r = 0; r < 8; r++) {
        int idx = r * 256 + t;
        int m = idx >> 5, j = idx & 31;
        uint4 v = *(const uint4*)(Xp + (long long)m * 256 + j * 8);
        *(uint4*)&tA[((m << 5) + (j ^ (m & 7))) * 8] = v;
    }
    __syncthreads();
    const int w = t >> 6, lane = t & 63, lrow = lane & 15, lq = lane >> 4;
    const int n0w = w * 64;
    const unsigned short* Wp = Wm + ((long long)d * 256 + n0w) * 256;
    floatx4 acc[4][4];
#pragma unroll
    for (int rt = 0; rt < 4; rt++)
#pragma unroll
        for (int ct = 0; ct < 4; ct++) acc[rt][ct] = (floatx4)(0.f);
    gemm_phase<256, 4>(tA, Wp, lrow, lq, acc);
    __syncthreads();  // tA dead; reuse for h staging
#pragma unroll
    for (int ct = 0; ct < 4; ct++) {
        float s = 0.f, ss = 0.f;
#pragma unroll
        for (int rt = 0; rt < 4; rt++)
#pragma unroll
            for (int r = 0; r < 4; r++) { float v = acc[rt][ct][r]; s += v; ss += v * v; }
        s += __shfl_down(s, 32); ss += __shfl_down(ss, 32);
        s += __shfl_down(s, 16); ss += __shfl_down(ss, 16);
        if (lane < 16) {
            atomicAdd(&gsum[d * 256 + n0w + ct * 16 + lane], s);
            atomicAdd(&gssq[d * 256 + n0w + ct * 16 + lane], ss);
        }
        int n = n0w + ct * 16 + lrow;
        int jj = n >> 3, sub = n & 7;
#pragma unroll
        for (int rt = 0; rt < 4; rt++)
#pragma unroll
            for (int r = 0; r < 4; r++) {
                int m = rt * 16 + lq * 4 + r;
                tA[((m << 5) + (jj ^ (m & 7))) * 8 + sub] = f2b(acc[rt][ct][r]);
            }
    }
    __syncthreads();
    unsigned short* Op = hOut + ((long long)d * BATCH + m0) * 256;
#pragma unroll
    for (int r = 0; r < 8; r++) {
        int idx = r * 256 + t;
        int m = idx >> 5, j = idx & 31;
        *(uint4*)(Op + (long long)m * 256 + j * 8) = *(const uint4*)&tA[((m << 5) + (j ^ (m & 7))) * 8];
    }
}

// ---------------------------------------------------------------------------
// fused2_k<N, NH, FINAL>: gate path (g1, g2) + BN/gate epilogue on h_l + next
// layer h GEMM (K=N -> NH) with stats+store.
// One 32KB LDS buffer cycled: gin -> g1b -> h -> X -> h_next.
// T14: h tile loads issued to regs BEFORE g1; LDS write after g2's barrier.
template <int N, int NH, bool FINAL>
__global__ __launch_bounds__(256, 2) void fused2_k(
    const unsigned short* __restrict__ gin,
    const unsigned short* __restrict__ hIn,   // [d][B][N]
    const unsigned short* __restrict__ W1,    // [d][N][256]
    const unsigned short* __restrict__ W2,    // [d][N][N]
    const unsigned short* __restrict__ WmN,   // [d][NH][N]
    const float* __restrict__ gb1, const float* __restrict__ gb2,
    const float* __restrict__ gsum, const float* __restrict__ gssq,
    const float* __restrict__ gma, const float* __restrict__ bta, float invB,
    unsigned short* __restrict__ hNext,       // [d][B][NH]
    float* __restrict__ gsumN, float* __restrict__ gssqN,
    const int* __restrict__ dom, const float* __restrict__ fw,
    const float* __restrict__ fb, float* __restrict__ outp) {
    constexpr int GG = N / 8;
    constexpr int NW = N / 4, CT = NW / 16;
    constexpr int NWH = NH / 4, CTH = NH / 64;
    constexpr int GH = NH / 8;
    constexpr int HREG = TM * GG / 256;  // N=256:8, 128:4, 64:2
    __shared__ __align__(16) unsigned short buf[TM * 256];
    const int t = threadIdx.x;
    const int d = blockIdx.y;
    const int m0 = blockIdx.x * TM;
    const int w = t >> 6, lane = t & 63, lrow = lane & 15, lq = lane >> 4;
    const int n0w = w * NW;

    {  // stage gin tile (TM x 256), XOR-swizzled granules
        const unsigned short* Gp = gin + (long long)m0 * 256;
#pragma unroll
        for (int r = 0; r < 8; r++) {
            int idx = r * 256 + t;
            int m = idx >> 5, j = idx & 31;
            uint4 v = *(const uint4*)(Gp + (long long)m * 256 + j * 8);
            *(uint4*)&buf[((m << 5) + (j ^ (m & 7))) * 8] = v;
        }
    }
    // T14: issue h tile loads NOW; latency hides under g1+g2 (~2 GEMM phases).
    uint4 hreg[HREG];
    {
        const unsigned short* Hp = hIn + ((long long)d * BATCH + m0) * N;
#pragma unroll
        for (int r = 0; r < HREG; r++) {
            int idx = r * 256 + t;
            int m = idx / GG, j = idx % GG;
            hreg[r] = *(const uint4*)(Hp + (long long)m * N + j * 8);
        }
    }
    __syncthreads();

    // ---- phase g1: acc1 = gin @ W1 (K=256)
    floatx4 acc1[4][CT];
#pragma unroll
    for (int rt = 0; rt < 4; rt++)
#pragma unroll
        for (int ct = 0; ct < CT; ct++) acc1[rt][ct] = (floatx4)(0.f);
    gemm_phase<256, CT>(buf, W1 + ((long long)d * N + n0w) * 256, lrow, lq, acc1);
    __syncthreads();  // gin dead; buf becomes g1b

    // g1 epilogue: relu(+b1) -> buf (bf16, swizzled granules, GG per row)
#pragma unroll
    for (int ct = 0; ct < CT; ct++) {
        int n = n0w + ct * 16 + lrow;
        float bs = gb1[d * N + n];
        int jj = n >> 3, sub = n & 7;
#pragma unroll
        for (int rt = 0; rt < 4; rt++)
#pragma unroll
            for (int r = 0; r < 4; r++) {
                int m = rt * 16 + lq * 4 + r;
                buf[(m * GG + (jj ^ (m & 7))) * 8 + sub] = f2b(fmaxf(acc1[rt][ct][r] + bs, 0.f));
            }
    }
    __syncthreads();

    // ---- phase g2: acc2 = g1 @ W2 (K=N); stays in AGPR until BN epilogue
    floatx4 acc2[4][CT];
#pragma unroll
    for (int rt = 0; rt < 4; rt++)
#pragma unroll
        for (int ct = 0; ct < CT; ct++) acc2[rt][ct] = (floatx4)(0.f);
    gemm_phase<N, CT>(buf, W2 + ((long long)d * N + n0w) * N, lrow, lq, acc2);
    __syncthreads();  // all g2 reads of buf done; buf becomes h tile

    {  // h tile: registers -> LDS (swizzled granules); loads long since landed
#pragma unroll
        for (int r = 0; r < HREG; r++) {
            int idx = r * 256 + t;
            int m = idx / GG, j = idx % GG;
            *(uint4*)&buf[(m * GG + (j ^ (m & 7))) * 8] = hreg[r];
        }
    }
    __syncthreads();

    // ---- epilogue in-place: X = relu(BN(h)) * gate, gate inline from acc2
#pragma unroll
    for (int ct = 0; ct < CT; ct++) {
        int n = n0w + ct * 16 + lrow;
        int i = d * N + n;
        float bs2 = gb2[i];
        float ma = gsum[i] * invB;
        float var = gssq[i] * invB - ma * ma;
        float sc = rsqrtf(var + 1e-5f) * gma[i];
        float sh = bta[i] - ma * sc;
        int jj = n >> 3, sub = n & 7;
#pragma unroll
        for (int rt = 0; rt < 4; rt++)
#pragma unroll
            for (int r = 0; r < 4; r++) {
                int m = rt * 16 + lq * 4 + r;
                int idx = (m * GG + (jj ^ (m & 7))) * 8 + sub;
                float hv = b2f(buf[idx]);
                float gate = 2.f / (1.f + __expf(-(acc2[rt][ct][r] + bs2)));
                buf[idx] = f2b(fmaxf(hv * sc + sh, 0.f) * gate);
            }
    }
    __syncthreads();

    if constexpr (!FINAL) {
        // ---- next-layer h GEMM: acch = X @ WmN (K=N -> NH), stats + store
        const int n0h = w * NWH;
        floatx4 acch[4][CTH];
#pragma unroll
        for (int rt = 0; rt < 4; rt++)
#pragma unroll
            for (int ct = 0; ct < CTH; ct++) acch[rt][ct] = (floatx4)(0.f);
        gemm_phase<N, CTH>(buf, WmN + ((long long)d * NH + n0h) * N, lrow, lq, acch);
        __syncthreads();  // X dead; buf becomes h_next staging
#pragma unroll
        for (int ct = 0; ct < CTH; ct++) {
            float s = 0.f, ss = 0.f;
#pragma unroll
            for (int rt = 0; rt < 4; rt++)
#pragma unroll
                for (int r = 0; r < 4; r++) { float v = acch[rt][ct][r]; s += v; ss += v * v; }
            s += __shfl_down(s, 32); ss += __shfl_down(ss, 32);
            s += __shfl_down(s, 16); ss += __shfl_down(ss, 16);
            if (lane < 16) {
                atomicAdd(&gsumN[d * NH + n0h + ct * 16 + lane], s);
                atomicAdd(&gssqN[d * NH + n0h + ct * 16 + lane], ss);
            }
            int n = n0h + ct * 16 + lrow;
            int jj = n >> 3, sub = n & 7;
#pragma unroll
            for (int rt = 0; rt < 4; rt++)
#pragma unroll
                for (int r = 0; r < 4; r++) {
                    int m = rt * 16 + lq * 4 + r;
                    buf[(m * GH + (jj ^ (m & 7))) * 8 + sub] = f2b(acch[rt][ct][r]);
                }
        }
        __syncthreads();
        unsigned short* Op = hNext + ((long long)d * BATCH + m0) * NH;
#pragma unroll
        for (int r = 0; r < TM * GH / 256; r++) {
            int idx = r * 256 + t;
            int m = idx / GH, j = idx % GH;
            *(uint4*)(Op + (long long)m * NH + j * 8) = *(const uint4*)&buf[(m * GH + (j ^ (m & 7))) * 8];
        }
    } else {
        // final: out[b] = sigmoid(X3[b] . finW[d] + finb[d]) where d == dom[b]
        // X3 in buf, TM=64 rows x 64 cols swizzled (GG=8); 4 threads/row.
        int m = t >> 2, q = t & 3;
        const float* fwp = fw + d * 64;
        float s = 0.f;
#pragma unroll
        for (int g = 0; g < 2; g++) {
            int j = q * 2 + g;
            short8 v = *(const short8*)&buf[(m * 8 + (j ^ (m & 7))) * 8];
#pragma unroll
            for (int kk = 0; kk < 8; kk++)
                s += b2f((unsigned short)v[kk]) * fwp[j * 8 + kk];
        }
        s += __shfl_down(s, 1);
        s += __shfl_down(s, 2);
        if (q == 0) {
            int b = m0 + m;
            if (dom[b] == d) outp[b] = 1.f / (1.f + __expf(-(s + fb[d])));
        }
    }
}

// ---------------------------------------------------------------------------
extern "C" void kernel_launch(void* const* d_in, const int* in_sizes, int n_in,
                              void* d_out, int out_size, void* d_ws, size_t ws_size,
                              hipStream_t stream) {
    const int B = BATCH, D = NDOM;

    const int* id_idx = (const int*)d_in[0];
    const int* agn_idx = (const int*)d_in[1];
    const int* dom = (const int*)d_in[2];
    const float* id_t = (const float*)d_in[3];
    const float* agn_t = (const float*)d_in[4];
    const float *mlpW[3], *bng[3], *bnb[3], *gW1[3], *gb1[3], *gW2[3], *gb2[3];
    for (int i = 0; i < 3; i++) {
        int b0 = 5 + i * 8;
        mlpW[i] = (const float*)d_in[b0 + 0];
        bng[i] = (const float*)d_in[b0 + 2];
        bnb[i] = (const float*)d_in[b0 + 3];
        gW1[i] = (const float*)d_in[b0 + 4];
        gb1[i] = (const float*)d_in[b0 + 5];
        gW2[i] = (const float*)d_in[b0 + 6];
        gb2[i] = (const float*)d_in[b0 + 7];
    }
    const float* finW = (const float*)d_in[29];
    const float* finb = (const float*)d_in[30];

    char* wsc = (char*)d_ws;
    size_t off = 0;
    auto alloc = [&](size_t bytes) -> char* {
        char* p = wsc + off;
        off = (off + bytes + 255) & ~(size_t)255;
        return p;
    };

    struct { const float* src; int K, N; } mats[9] = {
        {mlpW[0], 256, 256}, {gW1[0], 256, 256}, {gW2[0], 256, 256},
        {mlpW[1], 256, 128}, {gW1[1], 256, 128}, {gW2[1], 128, 128},
        {mlpW[2], 128, 64},  {gW1[2], 256, 64},  {gW2[2], 64, 64}};
    unsigned pfx[10];
    pfx[0] = 0;
    for (int j = 0; j < 9; j++) pfx[j + 1] = pfx[j] + 4u * mats[j].K * mats[j].N;

    unsigned short* wt = (unsigned short*)alloc((size_t)pfx[9] * 2);
    unsigned short* gin = (unsigned short*)alloc((size_t)B * 256 * 2);
    float* stats = (float*)alloc((size_t)3 * 2 * D * 256 * 4);  // per layer: gsum, gssq
    unsigned short* h0 = (unsigned short*)alloc((size_t)D * B * 256 * 2);
    unsigned short* h1 = (unsigned short*)alloc((size_t)D * B * 128 * 2);
    unsigned short* h2 = h0;  // ALIAS: h0 dead after F0 reads it; h2 written in F1.

    PrepArgs pa;
    for (int j = 0; j < 9; j++) {
        pa.m[j].src = mats[j].src;
        pa.m[j].K = (unsigned)mats[j].K;
        pa.m[j].N = (unsigned)mats[j].N;
        pa.m[j].pfx = pfx[j];
        pa.m[j].total = 4u * mats[j].K * mats[j].N;
    }
    pa.stats = stats;
    pa.statsN = 3 * 2 * D * 256;
    pa.grand = pfx[9];

    const float invB = 1.f / (float)B;
    dim3 gs(B / TM, D);

    prep_k<<<dim3((pfx[9] + 255) / 256), 256, 0, stream>>>(pa, wt);
    embed_k<<<dim3(B * 16 / 256), 256, 0, stream>>>(id_idx, agn_idx, id_t, agn_t, gin);

    float* gsum0 = stats + 0 * 2 * D * 256; float* gssq0 = gsum0 + D * 256;
    float* gsum1 = stats + 1 * 2 * D * 256; float* gssq1 = gsum1 + D * 256;
    float* gsum2 = stats + 2 * 2 * D * 256; float* gssq2 = gsum2 + D * 256;

    // h0 = gin @ Wm0, stats0, store
    h0_k<<<gs, 256, 0, stream>>>(gin, wt + pfx[0], gsum0, gssq0, h0);

    // F0: gate0 + BN(h0)*gate -> X1 (LDS) -> h1 = X1 @ Wm1, stats1, store
    fused2_k<256, 128, false><<<gs, 256, 0, stream>>>(
        gin, h0, wt + pfx[1], wt + pfx[2], wt + pfx[3], gb1[0], gb2[0],
        gsum0, gssq0, bng[0], bnb[0], invB,
        h1, gsum1, gssq1, nullptr, nullptr, nullptr, nullptr);

    // F1: gate1 + BN(h1)*gate -> X2 -> h2 = X2 @ Wm2, stats2, store (h2 aliases h0)
    fused2_k<128, 64, false><<<gs, 256, 0, stream>>>(
        gin, h1, wt + pfx[4], wt + pfx[5], wt + pfx[6], gb1[1], gb2[1],
        gsum1, gssq1, bng[1], bnb[1], invB,
        h2, gsum2, gssq2, nullptr, nullptr, nullptr, nullptr);

    // F2: gate2 + BN(h2)*gate -> X3 -> final dot + sigmoid + domain select
    fused2_k<64, 64, true><<<gs, 256, 0, stream>>>(
        gin, h2, wt + pfx[7], wt + pfx[8], nullptr, gb1[2], gb2[2],
        gsum2, gssq2, bng[2], bnb[2], invB,
        nullptr, nullptr, nullptr, dom, finW, finb, (float*)d_out);
}

// Round 11
// 454.420 us; speedup vs baseline: 1.0517x; 1.0517x over previous
//
#include <hip/hip_runtime.h>

// PPNet forward, round 13: r9 + A-fragment prefetch (r10's hreg reverted).
// Evidence ledger:
//  - r10 falsifier fired: hreg[32] live across g1+g2 -> 224 total regs -> spill
//    (hbm 114->209MB). No-spill envelope bracketed: 192 OK (r9), 224 spills.
//  - r9 F0 = 138us, MfmaUtil 12.6%: per-kstep period ~620cyc vs 156cyc of MFMA
//    issue -> ~540cyc idle. B side already 2-deep prefetched; remaining serial
//    chain is the 4 cold ds_read_b128 A-reads (~120-150cyc) at each kstep top.
// => This round: A-prefetch one kstep ahead (a0/an rotate, +16 regs -> ~208,
//    inside the bracket). ds_read latency for k+1 hides under k's MFMA cluster.
// Falsifier: hbm_bytes > 150MB on F0 = spill -> revert to exact r9.

typedef __attribute__((ext_vector_type(8))) short short8;
typedef __attribute__((ext_vector_type(4))) float floatx4;

#define BATCH 32768
#define NDOM 4
#define TM 64

__device__ __forceinline__ unsigned short f2b(float f) {
    unsigned u = __float_as_uint(f);
    u += 0x7fffu + ((u >> 16) & 1u);  // round-to-nearest-even
    return (unsigned short)(u >> 16);
}
__device__ __forceinline__ float b2f(unsigned short h) {
    return __uint_as_float(((unsigned)h) << 16);
}

// ---------------------------------------------------------------------------
// Shared GEMM phase: acc += A(lds,swizzled) @ B(global rows, K-contiguous).
// 2-deep B prefetch (r9) + 1-deep A prefetch (this round). Fully unrolled.
template <int K, int CT>
__device__ __forceinline__ void gemm_phase(const unsigned short* lA,
                                           const unsigned short* __restrict__ Bp,
                                           int lrow, int lq, floatx4 (&acc)[4][CT]) {
    constexpr int G = K / 8;
    short8 b0[CT], b1[CT];
#pragma unroll
    for (int ct = 0; ct < CT; ct++)
        b0[ct] = *(const short8*)(Bp + (long long)(ct * 16 + lrow) * K + lq * 8);
    if constexpr (K > 32) {
#pragma unroll
        for (int ct = 0; ct < CT; ct++)
            b1[ct] = *(const short8*)(Bp + (long long)(ct * 16 + lrow) * K + 32 + lq * 8);
    }
    short8 a0[4];
#pragma unroll
    for (int rt = 0; rt < 4; rt++) {
        int m = rt * 16 + lrow;
        a0[rt] = *(const short8*)&lA[(m * G + (lq ^ (m & 7))) * 8];
    }
#pragma unroll
    for (int k0 = 0; k0 < K; k0 += 32) {
        short8 an[4];
        if (k0 + 32 < K) {  // compile-time (unrolled): A for kstep k0+32
#pragma unroll
            for (int rt = 0; rt < 4; rt++) {
                int m = rt * 16 + lrow;
                an[rt] = *(const short8*)&lA[(m * G + ((((k0 + 32) >> 3) | lq) ^ (m & 7))) * 8];
            }
        }
        short8 bn[CT];
        if (k0 + 64 < K) {  // B for kstep k0+64
#pragma unroll
            for (int ct = 0; ct < CT; ct++)
                bn[ct] = *(const short8*)(Bp + (long long)(ct * 16 + lrow) * K + k0 + 64 + lq * 8);
        }
#pragma unroll
        for (int rt = 0; rt < 4; rt++)
#pragma unroll
            for (int ct = 0; ct < CT; ct++)
                acc[rt][ct] = __builtin_amdgcn_mfma_f32_16x16x32_bf16(a0[rt], b0[ct], acc[rt][ct], 0, 0, 0);
        if (k0 + 32 < K) {
#pragma unroll
            for (int rt = 0; rt < 4; rt++) a0[rt] = an[rt];
        }
#pragma unroll
        for (int ct = 0; ct < CT; ct++) {
            b0[ct] = b1[ct];
            if (k0 + 64 < K) b1[ct] = bn[ct];
        }
    }
}

// ---------------------------------------------------------------------------
// Weight prep: fp32 (D,K,N) -> bf16 (D,N,K) packed; zero stat accumulators.
struct MatDesc { const float* src; unsigned K, N, pfx, total; };
struct PrepArgs { MatDesc m[9]; float* stats; unsigned statsN; unsigned grand; };

__global__ __launch_bounds__(256) void prep_k(PrepArgs a, unsigned short* __restrict__ wt) {
    unsigned e = blockIdx.x * 256 + threadIdx.x;
    if (e < a.statsN) a.stats[e] = 0.f;
    if (e >= a.grand) return;
    int j = 0;
    while (j < 8 && e >= a.m[j].pfx + a.m[j].total) j++;
    const unsigned K = a.m[j].K, N = a.m[j].N;
    const unsigned local = e - a.m[j].pfx;
    const unsigned kn = K * N;
    const unsigned d = local / kn;
    const unsigned r2 = local - d * kn;
    const unsigned n = r2 / K;
    const unsigned k = r2 - n * K;
    wt[e] = f2b(a.m[j].src[((long long)d * K + k) * N + n]);
}

// ---------------------------------------------------------------------------
__global__ __launch_bounds__(256) void embed_k(const int* __restrict__ idi, const int* __restrict__ agi,
                                               const float* __restrict__ idt, const float* __restrict__ agt,
                                               unsigned short* __restrict__ gin) {
    int t = blockIdx.x * 256 + threadIdx.x;  // B*16 threads, one per (b, 16-elem slot)
    int b = t >> 4, slot = t & 15;
    int f = slot & 7;
    const int* ip = (slot < 8) ? idi : agi;
    const float* tab = (slot < 8) ? idt : agt;
    int ix = ip[b * 8 + f];
    const float* src = tab + ((long long)f * 100000 + ix) * 16;
    unsigned short tmp[16];
#pragma unroll
    for (int j = 0; j < 16; j++) tmp[j] = f2b(src[j]);
    unsigned short* dst = gin + (long long)b * 256 + slot * 16;
    *(uint4*)dst = *(const uint4*)tmp;
    *(uint4*)(dst + 8) = *(const uint4*)(tmp + 8);
}

// ---------------------------------------------------------------------------
// h0_k: h0 = gin @ Wm0, stats0 atomics, store h0 bf16.
__global__ __launch_bounds__(256, 2) void h0_k(
    const unsigned short* __restrict__ gin,
    const unsigned short* __restrict__ Wm,   // [d][256][256]
    float* __restrict__ gsum, float* __restrict__ gssq,
    unsigned short* __restrict__ hOut) {     // [d][B][256]
    __shared__ __align__(16) unsigned short tA[TM * 256];
    const int t = threadIdx.x;
    const int d = blockIdx.y;
    const int m0 = blockIdx.x * TM;
    const unsigned short* Xp = gin + (long long)m0 * 256;
#pragma unroll
    for (int r = 0; r < 8; r++) {
        int idx = r * 256 + t;
        int m = idx >> 5, j = idx & 31;
        uint4 v = *(const uint4*)(Xp + (long long)m * 256 + j * 8);
        *(uint4*)&tA[((m << 5) + (j ^ (m & 7))) * 8] = v;
    }
    __syncthreads();
    const int w = t >> 6, lane = t & 63, lrow = lane & 15, lq = lane >> 4;
    const int n0w = w * 64;
    const unsigned short* Wp = Wm + ((long long)d * 256 + n0w) * 256;
    floatx4 acc[4][4];
#pragma unroll
    for (int rt = 0; rt < 4; rt++)
#pragma unroll
        for (int ct = 0; ct < 4; ct++) acc[rt][ct] = (floatx4)(0.f);
    gemm_phase<256, 4>(tA, Wp, lrow, lq, acc);
    __syncthreads();  // tA dead; reuse for h staging
#pragma unroll
    for (int ct = 0; ct < 4; ct++) {
        float s = 0.f, ss = 0.f;
#pragma unroll
        for (int rt = 0; rt < 4; rt++)
#pragma unroll
            for (int r = 0; r < 4; r++) { float v = acc[rt][ct][r]; s += v; ss += v * v; }
        s += __shfl_down(s, 32); ss += __shfl_down(ss, 32);
        s += __shfl_down(s, 16); ss += __shfl_down(ss, 16);
        if (lane < 16) {
            atomicAdd(&gsum[d * 256 + n0w + ct * 16 + lane], s);
            atomicAdd(&gssq[d * 256 + n0w + ct * 16 + lane], ss);
        }
        int n = n0w + ct * 16 + lrow;
        int jj = n >> 3, sub = n & 7;
#pragma unroll
        for (int rt = 0; rt < 4; rt++)
#pragma unroll
            for (int r = 0; r < 4; r++) {
                int m = rt * 16 + lq * 4 + r;
                tA[((m << 5) + (jj ^ (m & 7))) * 8 + sub] = f2b(acc[rt][ct][r]);
            }
    }
    __syncthreads();
    unsigned short* Op = hOut + ((long long)d * BATCH + m0) * 256;
#pragma unroll
    for (int r = 0; r < 8; r++) {
        int idx = r * 256 + t;
        int m = idx >> 5, j = idx & 31;
        *(uint4*)(Op + (long long)m * 256 + j * 8) = *(const uint4*)&tA[((m << 5) + (j ^ (m & 7))) * 8];
    }
}

// ---------------------------------------------------------------------------
// fused2_k<N, NH, FINAL>: gate path (g1, g2) + BN/gate epilogue on h_l (from
// global) + next-layer h GEMM (K=N -> NH) with stats+store.
// One 32KB LDS buffer cycled: gin -> g1b -> h -> X -> h_next.
// Acc sets strictly sequential (acc1 -> acc2 -> acch); gate inline from acc2.
template <int N, int NH, bool FINAL>
__global__ __launch_bounds__(256, 2) void fused2_k(
    const unsigned short* __restrict__ gin,
    const unsigned short* __restrict__ hIn,   // [d][B][N]
    const unsigned short* __restrict__ W1,    // [d][N][256]
    const unsigned short* __restrict__ W2,    // [d][N][N]
    const unsigned short* __restrict__ WmN,   // [d][NH][N]
    const float* __restrict__ gb1, const float* __restrict__ gb2,
    const float* __restrict__ gsum, const float* __restrict__ gssq,
    const float* __restrict__ gma, const float* __restrict__ bta, float invB,
    unsigned short* __restrict__ hNext,       // [d][B][NH]
    float* __restrict__ gsumN, float* __restrict__ gssqN,
    const int* __restrict__ dom, const float* __restrict__ fw,
    const float* __restrict__ fb, float* __restrict__ outp) {
    constexpr int GG = N / 8;
    constexpr int NW = N / 4, CT = NW / 16;
    constexpr int NWH = NH / 4, CTH = NH / 64;
    constexpr int GH = NH / 8;
    __shared__ __align__(16) unsigned short buf[TM * 256];
    const int t = threadIdx.x;
    const int d = blockIdx.y;
    const int m0 = blockIdx.x * TM;
    const int w = t >> 6, lane = t & 63, lrow = lane & 15, lq = lane >> 4;
    const int n0w = w * NW;

    {  // stage gin tile (TM x 256), XOR-swizzled granules
        const unsigned short* Gp = gin + (long long)m0 * 256;
#pragma unroll
        for (int r = 0; r < 8; r++) {
            int idx = r * 256 + t;
            int m = idx >> 5, j = idx & 31;
            uint4 v = *(const uint4*)(Gp + (long long)m * 256 + j * 8);
            *(uint4*)&buf[((m << 5) + (j ^ (m & 7))) * 8] = v;
        }
    }
    __syncthreads();

    // ---- phase g1: acc1 = gin @ W1 (K=256)
    floatx4 acc1[4][CT];
#pragma unroll
    for (int rt = 0; rt < 4; rt++)
#pragma unroll
        for (int ct = 0; ct < CT; ct++) acc1[rt][ct] = (floatx4)(0.f);
    gemm_phase<256, CT>(buf, W1 + ((long long)d * N + n0w) * 256, lrow, lq, acc1);
    __syncthreads();  // gin dead; buf becomes g1b

    // g1 epilogue: relu(+b1) -> buf (bf16, swizzled granules, GG per row)
#pragma unroll
    for (int ct = 0; ct < CT; ct++) {
        int n = n0w + ct * 16 + lrow;
        float bs = gb1[d * N + n];
        int jj = n >> 3, sub = n & 7;
#pragma unroll
        for (int rt = 0; rt < 4; rt++)
#pragma unroll
            for (int r = 0; r < 4; r++) {
                int m = rt * 16 + lq * 4 + r;
                buf[(m * GG + (jj ^ (m & 7))) * 8 + sub] = f2b(fmaxf(acc1[rt][ct][r] + bs, 0.f));
            }
    }
    __syncthreads();

    // ---- phase g2: acc2 = g1 @ W2 (K=N); stays in AGPR until BN epilogue
    floatx4 acc2[4][CT];
#pragma unroll
    for (int rt = 0; rt < 4; rt++)
#pragma unroll
        for (int ct = 0; ct < CT; ct++) acc2[rt][ct] = (floatx4)(0.f);
    gemm_phase<N, CT>(buf, W2 + ((long long)d * N + n0w) * N, lrow, lq, acc2);
    __syncthreads();  // all g2 reads of buf done; buf becomes h tile

    {  // stage h_l tile (TM x N), swizzled granules
        const unsigned short* Hp = hIn + ((long long)d * BATCH + m0) * N;
#pragma unroll
        for (int r = 0; r < TM * GG / 256; r++) {
            int idx = r * 256 + t;
            int m = idx / GG, j = idx % GG;
            uint4 v = *(const uint4*)(Hp + (long long)m * N + j * 8);
            *(uint4*)&buf[(m * GG + (j ^ (m & 7))) * 8] = v;
        }
    }
    __syncthreads();

    // ---- epilogue in-place: X = relu(BN(h)) * gate, gate inline from acc2
#pragma unroll
    for (int ct = 0; ct < CT; ct++) {
        int n = n0w + ct * 16 + lrow;
        int i = d * N + n;
        float bs2 = gb2[i];
        float ma = gsum[i] * invB;
        float var = gssq[i] * invB - ma * ma;
        float sc = rsqrtf(var + 1e-5f) * gma[i];
        float sh = bta[i] - ma * sc;
        int jj = n >> 3, sub = n & 7;
#pragma unroll
        for (int rt = 0; rt < 4; rt++)
#pragma unroll
            for (int r = 0; r < 4; r++) {
                int m = rt * 16 + lq * 4 + r;
                int idx = (m * GG + (jj ^ (m & 7))) * 8 + sub;
                float hv = b2f(buf[idx]);
                float gate = 2.f / (1.f + __expf(-(acc2[rt][ct][r] + bs2)));
                buf[idx] = f2b(fmaxf(hv * sc + sh, 0.f) * gate);
            }
    }
    __syncthreads();

    if constexpr (!FINAL) {
        // ---- next-layer h GEMM: acch = X @ WmN (K=N -> NH), stats + store
        const int n0h = w * NWH;
        floatx4 acch[4][CTH];
#pragma unroll
        for (int rt = 0; rt < 4; rt++)
#pragma unroll
            for (int ct = 0; ct < CTH; ct++) acch[rt][ct] = (floatx4)(0.f);
        gemm_phase<N, CTH>(buf, WmN + ((long long)d * NH + n0h) * N, lrow, lq, acch);
        __syncthreads();  // X dead; buf becomes h_next staging
#pragma unroll
        for (int ct = 0; ct < CTH; ct++) {
            float s = 0.f, ss = 0.f;
#pragma unroll
            for (int rt = 0; rt < 4; rt++)
#pragma unroll
                for (int r = 0; r < 4; r++) { float v = acch[rt][ct][r]; s += v; ss += v * v; }
            s += __shfl_down(s, 32); ss += __shfl_down(ss, 32);
            s += __shfl_down(s, 16); ss += __shfl_down(ss, 16);
            if (lane < 16) {
                atomicAdd(&gsumN[d * NH + n0h + ct * 16 + lane], s);
                atomicAdd(&gssqN[d * NH + n0h + ct * 16 + lane], ss);
            }
            int n = n0h + ct * 16 + lrow;
            int jj = n >> 3, sub = n & 7;
#pragma unroll
            for (int rt = 0; rt < 4; rt++)
#pragma unroll
                for (int r = 0; r < 4; r++) {
                    int m = rt * 16 + lq * 4 + r;
                    buf[(m * GH + (jj ^ (m & 7))) * 8 + sub] = f2b(acch[rt][ct][r]);
                }
        }
        __syncthreads();
        unsigned short* Op = hNext + ((long long)d * BATCH + m0) * NH;
#pragma unroll
        for (int r = 0; r < TM * GH / 256; r++) {
            int idx = r * 256 + t;
            int m = idx / GH, j = idx % GH;
            *(uint4*)(Op + (long long)m * NH + j * 8) = *(const uint4*)&buf[(m * GH + (j ^ (m & 7))) * 8];
        }
    } else {
        // final: out[b] = sigmoid(X3[b] . finW[d] + finb[d]) where d == dom[b]
        // X3 in buf, TM=64 rows x 64 cols swizzled (GG=8); 4 threads/row.
        int m = t >> 2, q = t & 3;
        const float* fwp = fw + d * 64;
        float s = 0.f;
#pragma unroll
        for (int g = 0; g < 2; g++) {
            int j = q * 2 + g;
            short8 v = *(const short8*)&buf[(m * 8 + (j ^ (m & 7))) * 8];
#pragma unroll
            for (int kk = 0; kk < 8; kk++)
                s += b2f((unsigned short)v[kk]) * fwp[j * 8 + kk];
        }
        s += __shfl_down(s, 1);
        s += __shfl_down(s, 2);
        if (q == 0) {
            int b = m0 + m;
            if (dom[b] == d) outp[b] = 1.f / (1.f + __expf(-(s + fb[d])));
        }
    }
}

// ---------------------------------------------------------------------------
extern "C" void kernel_launch(void* const* d_in, const int* in_sizes, int n_in,
                              void* d_out, int out_size, void* d_ws, size_t ws_size,
                              hipStream_t stream) {
    const int B = BATCH, D = NDOM;

    const int* id_idx = (const int*)d_in[0];
    const int* agn_idx = (const int*)d_in[1];
    const int* dom = (const int*)d_in[2];
    const float* id_t = (const float*)d_in[3];
    const float* agn_t = (const float*)d_in[4];
    const float *mlpW[3], *bng[3], *bnb[3], *gW1[3], *gb1[3], *gW2[3], *gb2[3];
    for (int i = 0; i < 3; i++) {
        int b0 = 5 + i * 8;
        mlpW[i] = (const float*)d_in[b0 + 0];
        bng[i] = (const float*)d_in[b0 + 2];
        bnb[i] = (const float*)d_in[b0 + 3];
        gW1[i] = (const float*)d_in[b0 + 4];
        gb1[i] = (const float*)d_in[b0 + 5];
        gW2[i] = (const float*)d_in[b0 + 6];
        gb2[i] = (const float*)d_in[b0 + 7];
    }
    const float* finW = (const float*)d_in[29];
    const float* finb = (const float*)d_in[30];

    char* wsc = (char*)d_ws;
    size_t off = 0;
    auto alloc = [&](size_t bytes) -> char* {
        char* p = wsc + off;
        off = (off + bytes + 255) & ~(size_t)255;
        return p;
    };

    struct { const float* src; int K, N; } mats[9] = {
        {mlpW[0], 256, 256}, {gW1[0], 256, 256}, {gW2[0], 256, 256},
        {mlpW[1], 256, 128}, {gW1[1], 256, 128}, {gW2[1], 128, 128},
        {mlpW[2], 128, 64},  {gW1[2], 256, 64},  {gW2[2], 64, 64}};
    unsigned pfx[10];
    pfx[0] = 0;
    for (int j = 0; j < 9; j++) pfx[j + 1] = pfx[j] + 4u * mats[j].K * mats[j].N;

    unsigned short* wt = (unsigned short*)alloc((size_t)pfx[9] * 2);
    unsigned short* gin = (unsigned short*)alloc((size_t)B * 256 * 2);
    float* stats = (float*)alloc((size_t)3 * 2 * D * 256 * 4);  // per layer: gsum, gssq
    unsigned short* h0 = (unsigned short*)alloc((size_t)D * B * 256 * 2);
    unsigned short* h1 = (unsigned short*)alloc((size_t)D * B * 128 * 2);
    unsigned short* h2 = h0;  // ALIAS: h0 dead after F0 reads it; h2 written in F1.

    PrepArgs pa;
    for (int j = 0; j < 9; j++) {
        pa.m[j].src = mats[j].src;
        pa.m[j].K = (unsigned)mats[j].K;
        pa.m[j].N = (unsigned)mats[j].N;
        pa.m[j].pfx = pfx[j];
        pa.m[j].total = 4u * mats[j].K * mats[j].N;
    }
    pa.stats = stats;
    pa.statsN = 3 * 2 * D * 256;
    pa.grand = pfx[9];

    const float invB = 1.f / (float)B;
    dim3 gs(B / TM, D);

    prep_k<<<dim3((pfx[9] + 255) / 256), 256, 0, stream>>>(pa, wt);
    embed_k<<<dim3(B * 16 / 256), 256, 0, stream>>>(id_idx, agn_idx, id_t, agn_t, gin);

    float* gsum0 = stats + 0 * 2 * D * 256; float* gssq0 = gsum0 + D * 256;
    float* gsum1 = stats + 1 * 2 * D * 256; float* gssq1 = gsum1 + D * 256;
    float* gsum2 = stats + 2 * 2 * D * 256; float* gssq2 = gsum2 + D * 256;

    // h0 = gin @ Wm0, stats0, store
    h0_k<<<gs, 256, 0, stream>>>(gin, wt + pfx[0], gsum0, gssq0, h0);

    // F0: gate0 + BN(h0)*gate -> X1 (LDS) -> h1 = X1 @ Wm1, stats1, store
    fused2_k<256, 128, false><<<gs, 256, 0, stream>>>(
        gin, h0, wt + pfx[1], wt + pfx[2], wt + pfx[3], gb1[0], gb2[0],
        gsum0, gssq0, bng[0], bnb[0], invB,
        h1, gsum1, gssq1, nullptr, nullptr, nullptr, nullptr);

    // F1: gate1 + BN(h1)*gate -> X2 -> h2 = X2 @ Wm2, stats2, store (h2 aliases h0)
    fused2_k<128, 64, false><<<gs, 256, 0, stream>>>(
        gin, h1, wt + pfx[4], wt + pfx[5], wt + pfx[6], gb1[1], gb2[1],
        gsum1, gssq1, bng[1], bnb[1], invB,
        h2, gsum2, gssq2, nullptr, nullptr, nullptr, nullptr);

    // F2: gate2 + BN(h2)*gate -> X3 -> final dot + sigmoid + domain select
    fused2_k<64, 64, true><<<gs, 256, 0, stream>>>(
        gin, h2, wt + pfx[7], wt + pfx[8], nullptr, gb1[2], gb2[2],
        gsum2, gssq2, bng[2], bnb[2], invB,
        nullptr, nullptr, nullptr, dom, finW, finb, (float*)d_out);
}